// Round 13
// baseline (162.507 us; speedup 1.0000x reference)
//
#include <hip/hip_runtime.h>
#include <math.h>
#include <limits.h>

namespace {
constexpr int BB   = 4;
constexpr int NCH  = 6;
constexpr int HH   = 512;
constexpr int WW   = 512;
constexpr int NCEN = 64;
constexpr int KSZ  = 21;
constexpr int PADR = 10;
constexpr int HW   = HH * WW;
constexpr int BOXSTRIDE = 640;       // per-(b,ci) blurbox slot (25*25 rounded up)

__device__ __forceinline__ int refl(int q, int n) {
    q = (q < 0) ? -q : q;
    q = (q >= n) ? (2 * n - 2 - q) : q;
    return q;
}

// ---------------------------------------------------------------------------
// Dense kernel, 32x32 tiles, 4 px/thread. Tile-pruned argmin:
//   ub = min_i maxdist2(c_i, tile);  keep i iff mindist2(c_i, tile) <= ub.
// Pruned i has d2(p) >= mindist2_i > ub >= d_win(p) strictly, so winners AND
// ties survive. Packed key 64*d2 + i (exact ints) keeps jnp.argmin tie-break.
// Theta via libm atan2f (fast poly FAILED isolation: absmax 1.6e-2, R7/R8).
// Also zeroes maxbuf/done counters (ws is 0xAA-poisoned; stream order puts
// these writes before k_blurnorm's atomics).
// ---------------------------------------------------------------------------
__global__ __launch_bounds__(256) void k_geom(
    const float* __restrict__ centers,   // [B][NCEN][2] (cy, cx)
    const float* __restrict__ gt,        // [B][6][H][W]
    float* __restrict__ out,             // [B][6][H][W]
    float* __restrict__ mask,            // [B][H][W]
    unsigned int* __restrict__ maxbuf,   // [B]
    unsigned int* __restrict__ done)     // [B]
{
    __shared__ float s_cxf[NCEN], s_cyf[NCEN];
    __shared__ int   s_kx[NCEN], s_ky8[NCEN], s_ki[NCEN];
    __shared__ int   s_cnt, s_hasv;

    const int b    = blockIdx.y;
    const int tid  = threadIdx.x;
    const int tIdx = blockIdx.x;          // 0..255
    const int r0   = (tIdx >> 4) * 32;    // tile row base (h)
    const int c0   = (tIdx & 15) * 32;    // tile col base (w)

    if (tIdx == 0 && tid == 0) { maxbuf[b] = 0u; done[b] = 0u; }

    if (tid < NCEN) {                     // wave 0 only: prune + compact
        float cy = centers[(b * NCEN + tid) * 2 + 0];
        float cx = centers[(b * NCEN + tid) * 2 + 1];
        bool valid = (cy > 0.0f) || (cx > 0.0f);
        s_cxf[tid] = cx;
        s_cyf[tid] = cy;
        // rows pair with cx, cols with cy (dx = h - cx, dy = w - cy)
        float r0f = (float)r0, r1f = (float)(r0 + 31);
        float c0f = (float)c0, c1f = (float)(c0 + 31);
        float drm = fmaxf(fmaxf(r0f - cx, cx - r1f), 0.0f);
        float dcm = fmaxf(fmaxf(c0f - cy, cy - c1f), 0.0f);
        float drM = fmaxf(cx - r0f, r1f - cx);
        float dcM = fmaxf(cy - c0f, c1f - cy);
        float mind2 = drm * drm + dcm * dcm;   // exact ints in f32
        float maxd2 = drM * drM + dcM * dcM;
        if (!valid) { mind2 = __int_as_float(0x7f800000); maxd2 = mind2; }
        float ub = maxd2;
#pragma unroll
        for (int off = 32; off > 0; off >>= 1)
            ub = fminf(ub, __shfl_xor(ub, off, 64));
        bool keep = valid && (mind2 <= ub);
        unsigned long long km = __ballot(keep);
        unsigned long long vm = __ballot(valid);
        if (keep) {
            int pos = __popcll(km & ((1ull << tid) - 1ull));
            s_kx[pos]  = (int)cx;
            s_ky8[pos] = ((int)cy) * 8;
            s_ki[pos]  = tid;              // ascending original index order
        }
        if (tid == 0) { s_cnt = (int)__popcll(km); s_hasv = (vm != 0ull) ? 1 : 0; }
    }
    __syncthreads();

    const int row = r0 + (tid >> 3);       // 32 rows, 8 threads/row
    const int wb  = c0 + (tid & 7) * 4;    // 4 consecutive pixels
    const int w8  = wb * 8;
    const int cnt = s_cnt;
    const bool hv = (s_hasv != 0);

    int b0 = INT_MAX, b1 = INT_MAX, b2 = INT_MAX, b3 = INT_MAX;
    for (int k = 0; k < cnt; ++k) {
        int dr   = row - s_kx[k];
        int base = (__mul24(dr, dr) << 6) + s_ki[k];   // 64*dr^2 + i
        int icy8 = s_ky8[k];
        int d0 = w8      - icy8; b0 = min(b0, __mul24(d0, d0) + base);
        int d1 = w8 + 8  - icy8; b1 = min(b1, __mul24(d1, d1) + base);
        int d2 = w8 + 16 - icy8; b2 = min(b2, __mul24(d2, d2) + base);
        int d3 = w8 + 24 - icy8; b3 = min(b3, __mul24(d3, d3) + base);
    }
    int bi[4] = { b0 & 63, b1 & 63, b2 & 63, b3 & 63 };

    float aR[4], aT[4], aS[4], aC[4], aM[4];
    const float fh = (float)row;
#pragma unroll
    for (int j = 0; j < 4; ++j) {
        float cxw = s_cxf[bi[j]];
        float cyw = s_cyf[bi[j]];
        float gX = cxw - fh;
        float gY = cyw - (float)(wb + j);
        float r2 = gX * gX + gY * gY;      // exact small integers
        bool rpos = r2 > 0.0f;
        float R = rpos ? sqrtf(r2) : 0.0f;
        aR[j] = R;
        aT[j] = atan2f(gY, rpos ? gX : 1.0f);
        float invR = rpos ? (1.0f / R) : 0.0f;
        aS[j] = rpos ? gY * invR : 0.0f;   // sin(atan2(gY,gX)) == gY/R
        aC[j] = rpos ? gX * invR : 1.0f;   // cos(atan2(gY,gX)) == gX/R
        bool nearc = (fabsf(gX) < 3.0f) && (fabsf(gY) < 3.0f);
        aM[j] = (hv && nearc) ? 1.0f : 0.0f;
    }

    const size_t base = (size_t)b * NCH * HW + (size_t)(row * WW + wb);
    if (hv) {
        *(float4*)&out[base + 0 * (size_t)HW] = make_float4(aR[0], aR[1], aR[2], aR[3]);
        *(float4*)&out[base + 1 * (size_t)HW] = make_float4(aT[0], aT[1], aT[2], aT[3]);
        *(float4*)&out[base + 2 * (size_t)HW] = make_float4(aS[0], aS[1], aS[2], aS[3]);
        *(float4*)&out[base + 3 * (size_t)HW] = make_float4(aC[0], aC[1], aC[2], aC[3]);
    } else {
        *(float4*)&out[base + 0 * (size_t)HW] = *(const float4*)&gt[base + 0 * (size_t)HW];
        *(float4*)&out[base + 1 * (size_t)HW] = *(const float4*)&gt[base + 1 * (size_t)HW];
        *(float4*)&out[base + 2 * (size_t)HW] = *(const float4*)&gt[base + 2 * (size_t)HW];
        *(float4*)&out[base + 3 * (size_t)HW] = *(const float4*)&gt[base + 3 * (size_t)HW];
    }
    *(float4*)&out[base + 4 * (size_t)HW] = *(const float4*)&gt[base + 4 * (size_t)HW];
    *(float4*)&out[base + 5 * (size_t)HW] = make_float4(0.f, 0.f, 0.f, 0.f);
    *(float4*)&mask[(size_t)b * HW + (size_t)(row * WW + wb)] =
        make_float4(aM[0], aM[1], aM[2], aM[3]);
}

// ---------------------------------------------------------------------------
// Fused sparse blur + normalize, DEADLOCK-FREE (no spin; canonical
// last-block-reduces pattern). Every block (valid or not) takes a ticket
// after a fence; the block drawing ticket NCEN-1 normalizes ALL valid boxes
// of its batch from blurbox ws. Ticket RMW on done[b] + __threadfence gives
// cross-XCD visibility of blurbox/maxbuf. Overlapping boxes hold
// bit-identical values (same FMA chains) -> duplicate writes benign.
// ---------------------------------------------------------------------------
__global__ __launch_bounds__(256) void k_blurnorm(
    const float* __restrict__ centers,
    const float* __restrict__ mask,
    const float* __restrict__ g2d,
    float* __restrict__ blurbox,
    unsigned int* __restrict__ maxbuf,
    unsigned int* __restrict__ done,
    float* __restrict__ out)
{
    const int b   = blockIdx.y;
    const int ci  = blockIdx.x;
    const int tid = threadIdx.x;
    float cy = centers[(b * NCEN + ci) * 2 + 0];
    float cx = centers[(b * NCEN + ci) * 2 + 1];
    const bool bvalid = (cy > 0.0f) || (cx > 0.0f);

    __shared__ float k1[KSZ];
    __shared__ float patch[45 * 48];
    __shared__ float tmp[25 * 46];
    __shared__ int   s_ticket;

    if (bvalid) {
        const int icx = (int)cx, icy = (int)cy;
        const int rA = max(icx - 12, 0), rB = min(icx + 12, HH - 1);
        const int cA = max(icy - 12, 0), cB = min(icy + 12, WW - 1);
        const int pr0 = max(rA - PADR, 0), pr1 = min(rB + PADR, HH - 1);
        const int pc0 = max(cA - PADR, 0), pc1 = min(cB + PADR, WW - 1);
        const int nr = pr1 - pr0 + 1, nc = pc1 - pc0 + 1;   // <= 45
        const int nh = rB - rA + 1,  nw = cB - cA + 1;      // <= 25

        if (tid < KSZ) {
            float s = 0.0f;
#pragma unroll
            for (int j = 0; j < KSZ; ++j) s += g2d[tid * KSZ + j];
            k1[tid] = s;                 // exact 1D factor: row sums of g2d
        }
        const float* mb = mask + (size_t)b * HW;
        for (int e = tid; e < nr * nc; e += 256) {
            int r = e / nc, c = e - r * nc;
            patch[r * 48 + c] = mb[(pr0 + r) * WW + (pc0 + c)];
        }
        __syncthreads();

        for (int e = tid; e < nh * nc; e += 256) {
            int lr = e / nc, j = e - lr * nc;
            int r  = rA + lr;
            float acc = 0.0f;
#pragma unroll
            for (int dv = -PADR; dv <= PADR; ++dv) {
                int q = refl(r + dv, HH);
                acc = fmaf(k1[dv + PADR], patch[(q - pr0) * 48 + j], acc);
            }
            tmp[lr * 46 + j] = acc;
        }
        __syncthreads();

        float vmax = 0.0f;
        float* bx = blurbox + (size_t)(b * NCEN + ci) * BOXSTRIDE;
        for (int e = tid; e < nh * nw; e += 256) {
            int lr = e / nw, j = e - lr * nw;
            int w  = cA + j;
            float acc = 0.0f;
#pragma unroll
            for (int d = -PADR; d <= PADR; ++d) {
                int q = refl(w + d, WW);
                acc = fmaf(k1[d + PADR], tmp[lr * 46 + (q - pc0)], acc);
            }
            bx[lr * 25 + j] = acc;
            vmax = fmaxf(vmax, acc);
        }
#pragma unroll
        for (int off = 32; off > 0; off >>= 1)
            vmax = fmaxf(vmax, __shfl_down(vmax, off, 64));
        __shared__ float swr[4];
        const int lane = tid & 63, wid = tid >> 6;
        if (lane == 0) swr[wid] = vmax;
        __syncthreads();
        if (tid == 0) {
            float m = fmaxf(fmaxf(swr[0], swr[1]), fmaxf(swr[2], swr[3]));
            atomicMax(&maxbuf[b], __float_as_uint(m));  // nonneg: uint order == float
        }
        __syncthreads();
    }

    // ---- ticket (every block, valid or not; no waiting anywhere) ----
    __threadfence();                      // blurbox/maxbuf visible before ticket
    if (tid == 0) s_ticket = (int)atomicAdd(&done[b], 1u);
    __syncthreads();
    if (s_ticket != NCEN - 1) return;     // only the LAST block proceeds

    // ---- last block: all 64 tickets drawn => all stores fenced & visible ----
    __threadfence();
    const float inv =
        1.0f / fmaxf(__uint_as_float(atomicAdd(&maxbuf[b], 0u)), 1e-12f);
    float* o5 = out + ((size_t)b * NCH + 5) * HW;
    for (int c2 = 0; c2 < NCEN; ++c2) {
        float cy2 = centers[(b * NCEN + c2) * 2 + 0];
        float cx2 = centers[(b * NCEN + c2) * 2 + 1];
        if (!((cy2 > 0.0f) || (cx2 > 0.0f))) continue;
        const int icx = (int)cx2, icy = (int)cy2;
        const int rA = max(icx - 12, 0), rB = min(icx + 12, HH - 1);
        const int cA = max(icy - 12, 0), cB = min(icy + 12, WW - 1);
        const int nh = rB - rA + 1, nw = cB - cA + 1;
        const float* bx = blurbox + (size_t)(b * NCEN + c2) * BOXSTRIDE;
        for (int e = tid; e < nh * nw; e += 256) {
            int lr = e / nw, j = e - lr * nw;
            o5[(rA + lr) * WW + (cA + j)] = bx[lr * 25 + j] * inv;
        }
    }
}

} // namespace

extern "C" void kernel_launch(void* const* d_in, const int* in_sizes, int n_in,
                              void* d_out, int out_size, void* d_ws, size_t ws_size,
                              hipStream_t stream) {
    (void)in_sizes; (void)n_in; (void)out_size; (void)ws_size;
    const float* centers = (const float*)d_in[0];
    const float* gt      = (const float*)d_in[1];
    const float* g2d     = (const float*)d_in[2];
    float* out  = (float*)d_out;
    float* mask = (float*)d_ws;                                   // BB*HW floats
    float* blurbox = (float*)d_ws + (size_t)BB * HW;              // BB*NCEN*640 floats
    unsigned int* maxbuf =
        (unsigned int*)((float*)d_ws + (size_t)BB * HW + (size_t)BB * NCEN * BOXSTRIDE);
    unsigned int* done = maxbuf + BB;

    dim3 gridG(256, BB);                       // 16x16 tiles of 32x32 px
    k_geom<<<gridG, 256, 0, stream>>>(centers, gt, out, mask, maxbuf, done);
    dim3 gridS(NCEN, BB);
    k_blurnorm<<<gridS, 256, 0, stream>>>(centers, mask, g2d, blurbox, maxbuf, done, out);
}

// Round 14
// 95.767 us; speedup vs baseline: 1.6969x; 1.6969x over previous
//
#include <hip/hip_runtime.h>
#include <math.h>
#include <limits.h>

namespace {
constexpr int BB   = 4;
constexpr int NCH  = 6;
constexpr int HH   = 512;
constexpr int WW   = 512;
constexpr int NCEN = 64;
constexpr int KSZ  = 21;
constexpr int PADR = 10;
constexpr int HW   = HH * WW;
constexpr int BOXSTRIDE = 640;       // per-(b,ci) blurbox slot (25*25 rounded up)

__device__ __forceinline__ int refl(int q, int n) {
    q = (q < 0) ? -q : q;
    q = (q >= n) ? (2 * n - 2 - q) : q;
    return q;
}

// ---------------------------------------------------------------------------
// Dense kernel, 32x32 tiles, 4 px/thread. Tile-pruned argmin:
//   ub = min_i maxdist2(c_i, tile);  keep i iff mindist2(c_i, tile) <= ub.
// Pruned i has d2(p) >= mindist2_i > ub >= d_win(p) strictly, so winners AND
// ties survive. Packed key 64*d2 + i (exact ints) keeps jnp.argmin tie-break.
// Theta via libm atan2f (fast poly FAILED isolation: absmax 1.6e-2, R7/R8).
// R13 lesson: last-block-fused normalize serializes ~40K px on one CU
// (84 us, VALUBusy 3%) -> keep the wide 3-dispatch structure (R8: 94.7 us).
// ---------------------------------------------------------------------------
__global__ __launch_bounds__(256) void k_geom(
    const float* __restrict__ centers,   // [B][NCEN][2] (cy, cx)
    const float* __restrict__ gt,        // [B][6][H][W]
    float* __restrict__ out,             // [B][6][H][W]
    float* __restrict__ mask,            // [B][H][W]
    unsigned int* __restrict__ maxbuf)   // [B]
{
    __shared__ float s_cxf[NCEN], s_cyf[NCEN];
    __shared__ int   s_kx[NCEN], s_ky8[NCEN], s_ki[NCEN];
    __shared__ int   s_cnt, s_hasv;

    const int b    = blockIdx.y;
    const int tid  = threadIdx.x;
    const int tIdx = blockIdx.x;          // 0..255
    const int r0   = (tIdx >> 4) * 32;    // tile row base (h)
    const int c0   = (tIdx & 15) * 32;    // tile col base (w)

    if (tIdx == 0 && tid == 0) maxbuf[b] = 0u;   // ws is 0xAA-poisoned

    if (tid < NCEN) {                     // wave 0 only: prune + compact
        float cy = centers[(b * NCEN + tid) * 2 + 0];
        float cx = centers[(b * NCEN + tid) * 2 + 1];
        bool valid = (cy > 0.0f) || (cx > 0.0f);
        s_cxf[tid] = cx;
        s_cyf[tid] = cy;
        // rows pair with cx, cols with cy (dx = h - cx, dy = w - cy)
        float r0f = (float)r0, r1f = (float)(r0 + 31);
        float c0f = (float)c0, c1f = (float)(c0 + 31);
        float drm = fmaxf(fmaxf(r0f - cx, cx - r1f), 0.0f);
        float dcm = fmaxf(fmaxf(c0f - cy, cy - c1f), 0.0f);
        float drM = fmaxf(cx - r0f, r1f - cx);
        float dcM = fmaxf(cy - c0f, c1f - cy);
        float mind2 = drm * drm + dcm * dcm;   // exact ints in f32
        float maxd2 = drM * drM + dcM * dcM;
        if (!valid) { mind2 = __int_as_float(0x7f800000); maxd2 = mind2; }
        float ub = maxd2;
#pragma unroll
        for (int off = 32; off > 0; off >>= 1)
            ub = fminf(ub, __shfl_xor(ub, off, 64));
        bool keep = valid && (mind2 <= ub);
        unsigned long long km = __ballot(keep);
        unsigned long long vm = __ballot(valid);
        if (keep) {
            int pos = __popcll(km & ((1ull << tid) - 1ull));
            s_kx[pos]  = (int)cx;
            s_ky8[pos] = ((int)cy) * 8;
            s_ki[pos]  = tid;              // ascending original index order
        }
        if (tid == 0) { s_cnt = (int)__popcll(km); s_hasv = (vm != 0ull) ? 1 : 0; }
    }
    __syncthreads();

    const int row = r0 + (tid >> 3);       // 32 rows, 8 threads/row
    const int wb  = c0 + (tid & 7) * 4;    // 4 consecutive pixels
    const int w8  = wb * 8;
    const int cnt = s_cnt;
    const bool hv = (s_hasv != 0);

    int b0 = INT_MAX, b1 = INT_MAX, b2 = INT_MAX, b3 = INT_MAX;
    for (int k = 0; k < cnt; ++k) {
        int dr   = row - s_kx[k];
        int base = (__mul24(dr, dr) << 6) + s_ki[k];   // 64*dr^2 + i
        int icy8 = s_ky8[k];
        int d0 = w8      - icy8; b0 = min(b0, __mul24(d0, d0) + base);
        int d1 = w8 + 8  - icy8; b1 = min(b1, __mul24(d1, d1) + base);
        int d2 = w8 + 16 - icy8; b2 = min(b2, __mul24(d2, d2) + base);
        int d3 = w8 + 24 - icy8; b3 = min(b3, __mul24(d3, d3) + base);
    }
    int bi[4] = { b0 & 63, b1 & 63, b2 & 63, b3 & 63 };

    float aR[4], aT[4], aS[4], aC[4], aM[4];
    const float fh = (float)row;
#pragma unroll
    for (int j = 0; j < 4; ++j) {
        float cxw = s_cxf[bi[j]];
        float cyw = s_cyf[bi[j]];
        float gX = cxw - fh;
        float gY = cyw - (float)(wb + j);
        float r2 = gX * gX + gY * gY;      // exact small integers
        bool rpos = r2 > 0.0f;
        float R = rpos ? sqrtf(r2) : 0.0f;
        aR[j] = R;
        aT[j] = atan2f(gY, rpos ? gX : 1.0f);
        float invR = rpos ? (1.0f / R) : 0.0f;
        aS[j] = rpos ? gY * invR : 0.0f;   // sin(atan2(gY,gX)) == gY/R
        aC[j] = rpos ? gX * invR : 1.0f;   // cos(atan2(gY,gX)) == gX/R
        bool nearc = (fabsf(gX) < 3.0f) && (fabsf(gY) < 3.0f);
        aM[j] = (hv && nearc) ? 1.0f : 0.0f;
    }

    const size_t base = (size_t)b * NCH * HW + (size_t)(row * WW + wb);
    if (hv) {
        *(float4*)&out[base + 0 * (size_t)HW] = make_float4(aR[0], aR[1], aR[2], aR[3]);
        *(float4*)&out[base + 1 * (size_t)HW] = make_float4(aT[0], aT[1], aT[2], aT[3]);
        *(float4*)&out[base + 2 * (size_t)HW] = make_float4(aS[0], aS[1], aS[2], aS[3]);
        *(float4*)&out[base + 3 * (size_t)HW] = make_float4(aC[0], aC[1], aC[2], aC[3]);
    } else {
        *(float4*)&out[base + 0 * (size_t)HW] = *(const float4*)&gt[base + 0 * (size_t)HW];
        *(float4*)&out[base + 1 * (size_t)HW] = *(const float4*)&gt[base + 1 * (size_t)HW];
        *(float4*)&out[base + 2 * (size_t)HW] = *(const float4*)&gt[base + 2 * (size_t)HW];
        *(float4*)&out[base + 3 * (size_t)HW] = *(const float4*)&gt[base + 3 * (size_t)HW];
    }
    *(float4*)&out[base + 4 * (size_t)HW] = *(const float4*)&gt[base + 4 * (size_t)HW];
    *(float4*)&out[base + 5 * (size_t)HW] = make_float4(0.f, 0.f, 0.f, 0.f);
    *(float4*)&mask[(size_t)b * HW + (size_t)(row * WW + wb)] =
        make_float4(aM[0], aM[1], aM[2], aM[3]);
}

// ---------------------------------------------------------------------------
// Sparse blur over box(center, 12): mask patch staged in LDS, separable blur
// from LDS, box result stored to ws (blurbox) + per-batch atomicMax.
// Overlapping boxes compute bit-identical values -> benign races.
// ---------------------------------------------------------------------------
__device__ __forceinline__ void load_k1(const float* __restrict__ g2d, float* k1) {
    if (threadIdx.x < KSZ) {
        float s = 0.0f;
#pragma unroll
        for (int j = 0; j < KSZ; ++j) s += g2d[threadIdx.x * KSZ + j];
        k1[threadIdx.x] = s;
    }
}

__global__ __launch_bounds__(256) void k_blur_sparse(
    const float* __restrict__ centers,
    const float* __restrict__ mask,
    const float* __restrict__ g2d,
    float* __restrict__ blurbox,
    unsigned int* __restrict__ maxbuf)
{
    const int b  = blockIdx.y;
    const int ci = blockIdx.x;
    float cy = centers[(b * NCEN + ci) * 2 + 0];
    float cx = centers[(b * NCEN + ci) * 2 + 1];
    if (!((cy > 0.0f) || (cx > 0.0f))) return;     // uniform exit before barriers
    const int icx = (int)cx, icy = (int)cy;
    const int rA = max(icx - 12, 0), rB = min(icx + 12, HH - 1);
    const int cA = max(icy - 12, 0), cB = min(icy + 12, WW - 1);
    const int pr0 = max(rA - PADR, 0), pr1 = min(rB + PADR, HH - 1);
    const int pc0 = max(cA - PADR, 0), pc1 = min(cB + PADR, WW - 1);
    const int nr = pr1 - pr0 + 1, nc = pc1 - pc0 + 1;   // <= 45
    const int nh = rB - rA + 1,  nw = cB - cA + 1;      // <= 25

    __shared__ float k1[KSZ];
    __shared__ float patch[45 * 48];
    __shared__ float tmp[25 * 46];
    load_k1(g2d, k1);

    const float* mb = mask + (size_t)b * HW;
    for (int e = threadIdx.x; e < nr * nc; e += 256) {
        int r = e / nc, c = e - r * nc;
        patch[r * 48 + c] = mb[(pr0 + r) * WW + (pc0 + c)];
    }
    __syncthreads();

    for (int e = threadIdx.x; e < nh * nc; e += 256) {
        int lr = e / nc, j = e - lr * nc;
        int r  = rA + lr;
        float acc = 0.0f;
#pragma unroll
        for (int dv = -PADR; dv <= PADR; ++dv) {
            int q = refl(r + dv, HH);
            acc = fmaf(k1[dv + PADR], patch[(q - pr0) * 48 + j], acc);
        }
        tmp[lr * 46 + j] = acc;
    }
    __syncthreads();

    float vmax = 0.0f;
    float* bx = blurbox + (size_t)(b * NCEN + ci) * BOXSTRIDE;
    for (int e = threadIdx.x; e < nh * nw; e += 256) {
        int lr = e / nw, j = e - lr * nw;
        int w  = cA + j;
        float acc = 0.0f;
#pragma unroll
        for (int d = -PADR; d <= PADR; ++d) {
            int q = refl(w + d, WW);
            acc = fmaf(k1[d + PADR], tmp[lr * 46 + (q - pc0)], acc);
        }
        bx[lr * 25 + j] = acc;
        vmax = fmaxf(vmax, acc);
    }
#pragma unroll
    for (int off = 32; off > 0; off >>= 1)
        vmax = fmaxf(vmax, __shfl_down(vmax, off, 64));
    __shared__ float swr[4];
    const int lane = threadIdx.x & 63, wid = threadIdx.x >> 6;
    if (lane == 0) swr[wid] = vmax;
    __syncthreads();
    if (threadIdx.x == 0) {
        float m = fmaxf(fmaxf(swr[0], swr[1]), fmaxf(swr[2], swr[3]));
        atomicMax(&maxbuf[b], __float_as_uint(m));   // nonneg: uint order == float order
    }
}

__global__ __launch_bounds__(256) void k_norm_sparse(
    const float* __restrict__ centers,
    const float* __restrict__ blurbox,
    const unsigned int* __restrict__ maxbuf,
    float* __restrict__ out)
{
    const int b  = blockIdx.y;
    const int ci = blockIdx.x;
    float cy = centers[(b * NCEN + ci) * 2 + 0];
    float cx = centers[(b * NCEN + ci) * 2 + 1];
    if (!((cy > 0.0f) || (cx > 0.0f))) return;
    const int icx = (int)cx, icy = (int)cy;
    const int rA = max(icx - 12, 0), rB = min(icx + 12, HH - 1);
    const int cA = max(icy - 12, 0), cB = min(icy + 12, WW - 1);
    const int nh = rB - rA + 1, nw = cB - cA + 1;

    const float inv = 1.0f / fmaxf(__uint_as_float(maxbuf[b]), 1e-12f);
    const float* bx = blurbox + (size_t)(b * NCEN + ci) * BOXSTRIDE;
    float* o5 = out + ((size_t)b * NCH + 5) * HW;
    for (int e = threadIdx.x; e < nh * nw; e += 256) {
        int lr = e / nw, j = e - lr * nw;
        o5[(rA + lr) * WW + (cA + j)] = bx[lr * 25 + j] * inv;  // overwrites k_geom's zero
    }
}

} // namespace

extern "C" void kernel_launch(void* const* d_in, const int* in_sizes, int n_in,
                              void* d_out, int out_size, void* d_ws, size_t ws_size,
                              hipStream_t stream) {
    (void)in_sizes; (void)n_in; (void)out_size; (void)ws_size;
    const float* centers = (const float*)d_in[0];
    const float* gt      = (const float*)d_in[1];
    const float* g2d     = (const float*)d_in[2];
    float* out  = (float*)d_out;
    float* mask = (float*)d_ws;                                   // BB*HW floats
    float* blurbox = (float*)d_ws + (size_t)BB * HW;              // BB*NCEN*640 floats
    unsigned int* maxbuf =
        (unsigned int*)((float*)d_ws + (size_t)BB * HW + (size_t)BB * NCEN * BOXSTRIDE);

    dim3 gridG(256, BB);                       // 16x16 tiles of 32x32 px
    k_geom<<<gridG, 256, 0, stream>>>(centers, gt, out, mask, maxbuf);
    dim3 gridS(NCEN, BB);
    k_blur_sparse<<<gridS, 256, 0, stream>>>(centers, mask, g2d, blurbox, maxbuf);
    k_norm_sparse<<<gridS, 256, 0, stream>>>(centers, blurbox, maxbuf, out);
}